// Round 5
// baseline (1334.618 us; speedup 1.0000x reference)
//
#include <hip/hip_runtime.h>
#include <math.h>

// ---------------- problem constants ----------------
static constexpr int   B_    = 4;
static constexpr int   N_    = 4096;
static constexpr int   BOX_  = 128;
static constexpr long long VOX_ = 1LL * BOX_ * BOX_ * BOX_;   // 2097152
static constexpr float EPS_IN_C  = 6.5f;
static constexpr float EPS_OUT_C = 79.0f;
static constexpr float QCONV_C   = 7046.52f;
static constexpr float KAPPA02_C = 0.8486f;
static constexpr float FOURPI_C  = 12.566370614359172f;

// ---------------- trilinear charge scatter (verified via output 0) ----------
__global__ void scatter_q_kernel(const float* __restrict__ coords,
                                 const float* __restrict__ params,
                                 const int*   __restrict__ num_atoms,
                                 float* __restrict__ q)
{
    int a = blockIdx.x * blockDim.x + threadIdx.x;
    if (a >= B_ * N_) return;
    int b = a >> 12;
    int n = a & (N_ - 1);
    if (n >= num_atoms[b]) return;

    float cx = coords[3 * a + 0];
    float cy = coords[3 * a + 1];
    float cz = coords[3 * a + 2];
    float chg = params[2 * a + 0] * QCONV_C;

    int ix0 = (int)floorf(cx), iy0 = (int)floorf(cy), iz0 = (int)floorf(cz);
    float fx = cx - (float)ix0, fy = cy - (float)iy0, fz = cz - (float)iz0;
    float wx[2] = {1.0f - fx, fx};
    float wy[2] = {1.0f - fy, fy};
    float wz[2] = {1.0f - fz, fz};

    float* qb = q + (long long)b * VOX_;
#pragma unroll
    for (int dx = 0; dx < 2; ++dx) {
        int ix = ix0 + dx;
        if ((unsigned)ix >= 128u) continue;
#pragma unroll
        for (int dy = 0; dy < 2; ++dy) {
            int iy = iy0 + dy;
            if ((unsigned)iy >= 128u) continue;
#pragma unroll
            for (int dz = 0; dz < 2; ++dz) {
                int iz = iz0 + dz;
                if ((unsigned)iz >= 128u) continue;
                atomicAdd(&qb[((long long)ix * 128 + iy) * 128 + iz],
                          chg * wx[dx] * wy[dy] * wz[dz]);
            }
        }
    }
}

// ---------------- gather-based eps, JAX-wrap-aware ----------------
// JAX .at[].add(mode='drop') wraps NEGATIVE scatter indices (+=128) before
// the OOB check; only idx>=128 is dropped. So voxel i receives weight from
// virtual axis coordinate i (direct) or i-128 (wrapped, only i>=123 possible).
// A 9-wide window cannot contain both, so per axis at most one contributes.
__device__ __forceinline__ bool axis_d2(float c, float o, int i, float& d2)
{
    int base = (int)floorf(c - o) - 4;     // window: [base, base+8]
    if ((unsigned)(i - base) <= 8u) {
        float d = (float)i + o - c;
        d2 += d * d;
        return true;
    }
    int vi = i - 128;                      // wrapped virtual coordinate
    if ((unsigned)(vi - base) <= 8u) {
        float d = (float)vi + o - c;
        d2 += d * d;
        return true;
    }
    return false;
}

__device__ __forceinline__ float gauss_contrib(float cx, float cy, float cz,
                                               float inv2s2,
                                               float ox, float oy, float oz,
                                               int ix, int iy, int iz)
{
    float d2 = 0.0f;
    if (!axis_d2(cx, ox, ix, d2)) return 0.0f;
    if (!axis_d2(cy, oy, iy, d2)) return 0.0f;
    if (!axis_d2(cz, oz, iz, d2)) return 0.0f;
    return expf(-d2 * inv2s2);
}

#define CAND_CAP 512

__global__ void eps_gather_kernel(const float* __restrict__ coords,
                                  const float* __restrict__ params,
                                  const int*   __restrict__ num_atoms,
                                  float* __restrict__ eps)   // [B][4][128^3]
{
    int tileId = blockIdx.x;            // B * 4096 tiles
    int b  = tileId >> 12;
    int t  = tileId & 4095;
    int tx = ((t >> 8) & 15) << 3;
    int ty = ((t >> 4) & 15) << 3;
    int tz = (t & 15) << 3;

    __shared__ float sx[CAND_CAP], sy[CAND_CAP], sz[CAND_CAP], sr[CAND_CAP];
    __shared__ int s_cnt;
    if (threadIdx.x == 0) s_cnt = 0;
    __syncthreads();

    int na = num_atoms[b];
    const float* cb = coords + (size_t)b * N_ * 3;
    const float* pb = params + (size_t)b * N_ * 2;

    float lox = (float)tx - 6.0f, hix = (float)tx + 14.0f;
    float loy = (float)ty - 6.0f, hiy = (float)ty + 14.0f;
    float loz = (float)tz - 6.0f, hiz = (float)tz + 14.0f;
    // high-edge tiles (t=120) also receive wrapped density from atoms near
    // the LOW face (virtual coords -5..-1 <- atoms with c < ~5.5)
    bool wx_ = (tx == 120), wy_ = (ty == 120), wz_ = (tz == 120);
    for (int n = threadIdx.x; n < na; n += blockDim.x) {
        float cx = cb[3 * n], cy = cb[3 * n + 1], cz = cb[3 * n + 2];
        bool okx = (cx >= lox && cx < hix) || (wx_ && cx < 6.0f);
        bool oky = (cy >= loy && cy < hiy) || (wy_ && cy < 6.0f);
        bool okz = (cz >= loz && cz < hiz) || (wz_ && cz < 6.0f);
        if (okx && oky && okz) {
            int slot = atomicAdd(&s_cnt, 1);
            if (slot < CAND_CAP) {
                sx[slot] = cx; sy[slot] = cy; sz[slot] = cz;
                sr[slot] = pb[2 * n + 1];
            }
        }
    }
    __syncthreads();
    int cnt = min(s_cnt, CAND_CAP);

    int lz = threadIdx.x & 7;
    int ly = (threadIdx.x >> 3) & 7;
    int lx = threadIdx.x >> 6;
    int ix = tx + lx, iy = ty + ly, iz = tz + lz;

    float r0 = 0.0f, r1 = 0.0f, r2 = 0.0f, r3 = 0.0f;
    for (int k = 0; k < cnt; ++k) {
        float cx = sx[k], cy = sy[k], cz = sz[k], r = sr[k];
        float sE = (r + 1.4f) * 0.5f;
        float sI = (r + 1.0f) * 0.5f;
        float iE = 1.0f / (2.0f * sE * sE);
        float iI = 1.0f / (2.0f * sI * sI);
        r0 += gauss_contrib(cx, cy, cz, iE, 0.5f, 0.0f, 0.0f, ix, iy, iz);
        r1 += gauss_contrib(cx, cy, cz, iE, 0.0f, 0.5f, 0.0f, ix, iy, iz);
        r2 += gauss_contrib(cx, cy, cz, iE, 0.0f, 0.0f, 0.5f, ix, iy, iz);
        r3 += gauss_contrib(cx, cy, cz, iI, 0.5f, 0.5f, 0.5f, ix, iy, iz);
    }

    size_t sp = ((size_t)ix * 128 + iy) * 128 + iz;
    float* eb = eps + (size_t)b * 4 * VOX_;
    eb[sp]                    = EPS_OUT_C + (EPS_IN_C - EPS_OUT_C) * fminf(fmaxf(r0, 0.0f), 1.0f);
    eb[sp + (size_t)VOX_]     = EPS_OUT_C + (EPS_IN_C - EPS_OUT_C) * fminf(fmaxf(r1, 0.0f), 1.0f);
    eb[sp + (size_t)VOX_ * 2] = EPS_OUT_C + (EPS_IN_C - EPS_OUT_C) * fminf(fmaxf(r2, 0.0f), 1.0f);
    eb[sp + (size_t)VOX_ * 3] = EPS_OUT_C + (EPS_IN_C - EPS_OUT_C) * fminf(fmaxf(r3, 0.0f), 1.0f);
}

// ---------------- Jacobi sweep (unchanged from round 4) ----------------
__global__ void jacobi_v2(const float* __restrict__ eps,
                          const float* __restrict__ q,
                          const float* __restrict__ pin,
                          float* __restrict__ pout)
{
    int bxy = blockIdx.x;                  // 0 .. B*128*128-1
    int b = bxy >> 14;
    int x = (bxy >> 7) & 127;
    int y = bxy & 127;
    int z = threadIdx.x;                   // 0..127

    size_t sp = ((size_t)x * 128 + y) * 128 + z;
    size_t g  = (size_t)b * (size_t)VOX_ + sp;
    const float* E = eps + (size_t)b * 4 * (size_t)VOX_;

    float ex = E[sp];
    float ey = E[sp + (size_t)VOX_];
    float ez = E[sp + (size_t)VOX_ * 2];
    float ek = E[sp + (size_t)VOX_ * 3];
    float exm = (x > 0) ? E[sp - 16384]                 : EPS_OUT_C;
    float eym = (y > 0) ? E[sp + (size_t)VOX_ - 128]    : EPS_OUT_C;
    float ezm = (z > 0) ? E[sp + (size_t)VOX_ * 2 - 1]  : EPS_OUT_C;

    float lam = (ek - EPS_IN_C) / (EPS_OUT_C - EPS_IN_C);
    lam = fminf(fmaxf(lam, 0.0f), 1.0f);
    float denom = ex + exm + ey + eym + ez + ezm + KAPPA02_C * lam;

    float pxp = (x < 127) ? pin[g + 16384] : 0.0f;
    float pxm = (x > 0)   ? pin[g - 16384] : 0.0f;
    float pyp = (y < 127) ? pin[g + 128]   : 0.0f;
    float pym = (y > 0)   ? pin[g - 128]   : 0.0f;
    float pzp = (z < 127) ? pin[g + 1]     : 0.0f;
    float pzm = (z > 0)   ? pin[g - 1]     : 0.0f;

    float num = ex * pxp + exm * pxm + ey * pyp + eym * pym
              + ez * pzp + ezm * pzm + FOURPI_C * q[g];
    pout[g] = num / denom;
}

// ---------------- launch ----------------
extern "C" void kernel_launch(void* const* d_in, const int* in_sizes, int n_in,
                              void* d_out, int out_size, void* d_ws, size_t ws_size,
                              hipStream_t stream)
{
    const float* coords    = (const float*)d_in[0];
    const float* params    = (const float*)d_in[1];
    const int*   num_atoms = (const int*)d_in[2];

    float* q   = (float*)d_out;                       // [B][128^3]
    float* eps = q + (size_t)B_ * VOX_;               // [B][4][128^3]
    float* phi = eps + (size_t)B_ * 4 * VOX_;         // [B][128^3]
    float* tmp = (float*)d_ws;                        // [B][128^3] scratch

    hipMemsetAsync(q, 0, (size_t)B_ * VOX_ * sizeof(float), stream);
    hipMemsetAsync(phi, 0, (size_t)B_ * VOX_ * sizeof(float), stream);

    scatter_q_kernel<<<(B_ * N_ + 255) / 256, 256, 0, stream>>>(coords, params, num_atoms, q);
    eps_gather_kernel<<<B_ * 4096, 512, 0, stream>>>(coords, params, num_atoms, eps);

    // 20 uniform sweeps; phi_0 (zeroed) in the phi slot.
    // odd iters: phi -> tmp ; even iters: tmp -> phi ; iter 20 lands in phi.
    int jb = B_ * 128 * 128;
    const float* cur = phi;
    for (int it = 1; it <= 20; ++it) {
        float* dst = (it & 1) ? tmp : phi;
        jacobi_v2<<<jb, 128, 0, stream>>>(eps, q, cur, dst);
        cur = dst;
    }
}

// Round 6
// 1233.692 us; speedup vs baseline: 1.0818x; 1.0818x over previous
//
#include <hip/hip_runtime.h>
#include <hip/hip_fp16.h>
#include <math.h>

// ---------------- problem constants ----------------
static constexpr int   B_    = 4;
static constexpr int   N_    = 4096;
static constexpr int   BOX_  = 128;
static constexpr long long VOX_ = 1LL * BOX_ * BOX_ * BOX_;   // 2097152
static constexpr float EPS_IN_C  = 6.5f;
static constexpr float EPS_OUT_C = 79.0f;
static constexpr float QCONV_C   = 7046.52f;
static constexpr float KAPPA02_C = 0.8486f;
static constexpr float FOURPI_C  = 12.566370614359172f;

// ---------------- trilinear charge scatter (verified) ----------
__global__ void scatter_q_kernel(const float* __restrict__ coords,
                                 const float* __restrict__ params,
                                 const int*   __restrict__ num_atoms,
                                 float* __restrict__ q)
{
    int a = blockIdx.x * blockDim.x + threadIdx.x;
    if (a >= B_ * N_) return;
    int b = a >> 12;
    int n = a & (N_ - 1);
    if (n >= num_atoms[b]) return;

    float cx = coords[3 * a + 0];
    float cy = coords[3 * a + 1];
    float cz = coords[3 * a + 2];
    float chg = params[2 * a + 0] * QCONV_C;

    int ix0 = (int)floorf(cx), iy0 = (int)floorf(cy), iz0 = (int)floorf(cz);
    float fx = cx - (float)ix0, fy = cy - (float)iy0, fz = cz - (float)iz0;
    float wx[2] = {1.0f - fx, fx};
    float wy[2] = {1.0f - fy, fy};
    float wz[2] = {1.0f - fz, fz};

    float* qb = q + (long long)b * VOX_;
#pragma unroll
    for (int dx = 0; dx < 2; ++dx) {
        int ix = ix0 + dx;
        if ((unsigned)ix >= 128u) continue;
#pragma unroll
        for (int dy = 0; dy < 2; ++dy) {
            int iy = iy0 + dy;
            if ((unsigned)iy >= 128u) continue;
#pragma unroll
            for (int dz = 0; dz < 2; ++dz) {
                int iz = iz0 + dz;
                if ((unsigned)iz >= 128u) continue;
                atomicAdd(&qb[((long long)ix * 128 + iy) * 128 + iz],
                          chg * wx[dx] * wy[dy] * wz[dz]);
            }
        }
    }
}

// ---------------- eps gather v2: separable per-axis weights in LDS ----------
// Weight semantics identical to verified round-5 axis_d2 (JAX wrap on negatives).
#define CAND_CAP 512
#define CHUNK 32

__global__ void eps_gather_v2(const float* __restrict__ coords,
                              const float* __restrict__ params,
                              const int*   __restrict__ num_atoms,
                              float* __restrict__ eps)   // [B][4][128^3]
{
    int tileId = blockIdx.x;            // B * 4096 tiles
    int b  = tileId >> 12;
    int t  = tileId & 4095;
    int tx = ((t >> 8) & 15) << 3;
    int ty = ((t >> 4) & 15) << 3;
    int tz = (t & 15) << 3;

    __shared__ float sx[CAND_CAP], sy[CAND_CAP], sz[CAND_CAP], sr[CAND_CAP];
    __shared__ float wts[CHUNK][9][8];   // [atom][axis*3+variant][tile pos]
    __shared__ int s_cnt;
    if (threadIdx.x == 0) s_cnt = 0;
    __syncthreads();

    int na = num_atoms[b];
    const float* cb = coords + (size_t)b * N_ * 3;
    const float* pb = params + (size_t)b * N_ * 2;

    float lox = (float)tx - 6.0f, hix = (float)tx + 14.0f;
    float loy = (float)ty - 6.0f, hiy = (float)ty + 14.0f;
    float loz = (float)tz - 6.0f, hiz = (float)tz + 14.0f;
    bool wx_ = (tx == 120), wy_ = (ty == 120), wz_ = (tz == 120);
    for (int n = threadIdx.x; n < na; n += blockDim.x) {
        float cx = cb[3 * n], cy = cb[3 * n + 1], cz = cb[3 * n + 2];
        bool okx = (cx >= lox && cx < hix) || (wx_ && cx < 6.0f);
        bool oky = (cy >= loy && cy < hiy) || (wy_ && cy < 6.0f);
        bool okz = (cz >= loz && cz < hiz) || (wz_ && cz < 6.0f);
        if (okx && oky && okz) {
            int slot = atomicAdd(&s_cnt, 1);
            if (slot < CAND_CAP) {
                sx[slot] = cx; sy[slot] = cy; sz[slot] = cz;
                sr[slot] = pb[2 * n + 1];
            }
        }
    }
    __syncthreads();
    int cnt = min(s_cnt, CAND_CAP);

    int lz = threadIdx.x & 7;
    int ly = (threadIdx.x >> 3) & 7;
    int lx = threadIdx.x >> 6;

    float r0 = 0.0f, r1 = 0.0f, r2 = 0.0f, r3 = 0.0f;

    for (int k0 = 0; k0 < cnt; k0 += CHUNK) {
        int nC = min(CHUNK, cnt - k0);
        __syncthreads();   // protect wts reuse across chunk iterations
        // Phase A: fill per-atom separable axis weights (72 expf per atom)
        for (int w = threadIdx.x; w < nC * 72; w += 512) {
            int ka  = w / 72;
            int rem = w - ka * 72;
            int vi  = rem >> 3;        // 0..8 = axis*3 + variant
            int pos = rem & 7;
            int axis = vi / 3, var = vi - axis * 3;
            int k = k0 + ka;
            float c     = (axis == 0) ? sx[k] : (axis == 1) ? sy[k] : sz[k];
            int   torig = (axis == 0) ? tx    : (axis == 1) ? ty    : tz;
            float r = sr[k];
            float sig = (var == 2) ? (r + 1.0f) * 0.5f : (r + 1.4f) * 0.5f;
            float off = (var == 0) ? 0.0f : 0.5f;
            float inv2s2 = 1.0f / (2.0f * sig * sig);
            int i = torig + pos;
            int base = (int)floorf(c - off) - 4;    // window [base, base+8]
            float wv = 0.0f;
            if ((unsigned)(i - base) <= 8u) {
                float d = (float)i + off - c;
                wv = expf(-d * d * inv2s2);
            } else if ((unsigned)(i - 128 - base) <= 8u) {   // JAX negative wrap
                float d = (float)(i - 128) + off - c;
                wv = expf(-d * d * inv2s2);
            }
            wts[ka][vi][pos] = wv;
        }
        __syncthreads();
        // Phase B: accumulate channels from separable products
        for (int ka = 0; ka < nC; ++ka) {
            float xE0 = wts[ka][0][lx], xE5 = wts[ka][1][lx], xI5 = wts[ka][2][lx];
            float yE0 = wts[ka][3][ly], yE5 = wts[ka][4][ly], yI5 = wts[ka][5][ly];
            float zE0 = wts[ka][6][lz], zE5 = wts[ka][7][lz], zI5 = wts[ka][8][lz];
            r0 += xE5 * yE0 * zE0;     // c0: off (.5,0,0)  sigE
            r1 += xE0 * yE5 * zE0;     // c1: off (0,.5,0)  sigE
            r2 += xE0 * yE0 * zE5;     // c2: off (0,0,.5)  sigE
            r3 += xI5 * yI5 * zI5;     // c3: off (.5,.5,.5) sigI
        }
    }

    int ix = tx + lx, iy = ty + ly, iz = tz + lz;
    size_t sp = ((size_t)ix * 128 + iy) * 128 + iz;
    float* eb = eps + (size_t)b * 4 * VOX_;
    eb[sp]                    = EPS_OUT_C + (EPS_IN_C - EPS_OUT_C) * fminf(fmaxf(r0, 0.0f), 1.0f);
    eb[sp + (size_t)VOX_]     = EPS_OUT_C + (EPS_IN_C - EPS_OUT_C) * fminf(fmaxf(r1, 0.0f), 1.0f);
    eb[sp + (size_t)VOX_ * 2] = EPS_OUT_C + (EPS_IN_C - EPS_OUT_C) * fminf(fmaxf(r2, 0.0f), 1.0f);
    eb[sp + (size_t)VOX_ * 3] = EPS_OUT_C + (EPS_IN_C - EPS_OUT_C) * fminf(fmaxf(r3, 0.0f), 1.0f);
}

// ---------------- coefficient pack: 8 fp16 per voxel ----------------
// {ex,exm,ey,eym,ez,ezm}/denom and 4*pi*q/denom
__global__ void coef_pack(const float* __restrict__ eps,
                          const float* __restrict__ q,
                          uint4* __restrict__ coef)
{
    int bxy = blockIdx.x;
    int b = bxy >> 14;
    int x = (bxy >> 7) & 127;
    int y = bxy & 127;
    int z = threadIdx.x;

    size_t sp = ((size_t)x * 128 + y) * 128 + z;
    size_t g  = (size_t)b * (size_t)VOX_ + sp;
    const float* E = eps + (size_t)b * 4 * (size_t)VOX_;

    float ex = E[sp];
    float ey = E[sp + (size_t)VOX_];
    float ez = E[sp + (size_t)VOX_ * 2];
    float ek = E[sp + (size_t)VOX_ * 3];
    float exm = (x > 0) ? E[sp - 16384]                 : EPS_OUT_C;
    float eym = (y > 0) ? E[sp + (size_t)VOX_ - 128]    : EPS_OUT_C;
    float ezm = (z > 0) ? E[sp + (size_t)VOX_ * 2 - 1]  : EPS_OUT_C;

    float lam = (ek - EPS_IN_C) / (EPS_OUT_C - EPS_IN_C);
    lam = fminf(fmaxf(lam, 0.0f), 1.0f);
    float denom = ex + exm + ey + eym + ez + ezm + KAPPA02_C * lam;
    float rcp = 1.0f / denom;

    __half2 h01 = __floats2half2_rn(ex  * rcp, exm * rcp);
    __half2 h23 = __floats2half2_rn(ey  * rcp, eym * rcp);
    __half2 h45 = __floats2half2_rn(ez  * rcp, ezm * rcp);
    __half2 h67 = __floats2half2_rn(FOURPI_C * q[g] * rcp, 0.0f);
    uint4 u;
    u.x = *(unsigned int*)&h01;
    u.y = *(unsigned int*)&h23;
    u.z = *(unsigned int*)&h45;
    u.w = *(unsigned int*)&h67;
    coef[g] = u;
}

// ---------------- Jacobi sweep v3: 4 z-voxels per thread, fp16 coefs --------
__global__ void jacobi_v3(const uint4* __restrict__ coef,
                          const float* __restrict__ pin,
                          float* __restrict__ pout)
{
    int tid = blockIdx.x * blockDim.x + threadIdx.x;   // 0 .. B*VOX/4-1
    size_t g4 = (size_t)tid * 4;
    int z4 = (int)(g4 & 127);          // 0,4,...,124
    int y  = (int)((g4 >> 7) & 127);
    int x  = (int)((g4 >> 14) & 127);

    float4 pcv = *reinterpret_cast<const float4*>(pin + g4);
    float4 z4v = make_float4(0.f, 0.f, 0.f, 0.f);
    float4 pxpv = (x < 127) ? *reinterpret_cast<const float4*>(pin + g4 + 16384) : z4v;
    float4 pxmv = (x > 0)   ? *reinterpret_cast<const float4*>(pin + g4 - 16384) : z4v;
    float4 pypv = (y < 127) ? *reinterpret_cast<const float4*>(pin + g4 + 128)   : z4v;
    float4 pymv = (y > 0)   ? *reinterpret_cast<const float4*>(pin + g4 - 128)   : z4v;
    float zpE = (z4 < 124) ? pin[g4 + 4] : 0.0f;
    float zmE = (z4 > 0)   ? pin[g4 - 1] : 0.0f;

    float pxp[4] = {pxpv.x, pxpv.y, pxpv.z, pxpv.w};
    float pxm[4] = {pxmv.x, pxmv.y, pxmv.z, pxmv.w};
    float pyp[4] = {pypv.x, pypv.y, pypv.z, pypv.w};
    float pym[4] = {pymv.x, pymv.y, pymv.z, pymv.w};
    float pzp[4] = {pcv.y, pcv.z, pcv.w, zpE};
    float pzm[4] = {zmE, pcv.x, pcv.y, pcv.z};

    float out[4];
#pragma unroll
    for (int j = 0; j < 4; ++j) {
        uint4 cu = coef[g4 + j];
        const __half2* h = reinterpret_cast<const __half2*>(&cu);
        float2 a01 = __half22float2(h[0]);
        float2 a23 = __half22float2(h[1]);
        float2 a45 = __half22float2(h[2]);
        float2 a67 = __half22float2(h[3]);
        out[j] = a01.x * pxp[j] + a01.y * pxm[j]
               + a23.x * pyp[j] + a23.y * pym[j]
               + a45.x * pzp[j] + a45.y * pzm[j]
               + a67.x;
    }
    *reinterpret_cast<float4*>(pout + g4) = make_float4(out[0], out[1], out[2], out[3]);
}

// ---------------- Jacobi sweep v2 (fallback path, verified) ----------------
__global__ void jacobi_v2(const float* __restrict__ eps,
                          const float* __restrict__ q,
                          const float* __restrict__ pin,
                          float* __restrict__ pout)
{
    int bxy = blockIdx.x;
    int b = bxy >> 14;
    int x = (bxy >> 7) & 127;
    int y = bxy & 127;
    int z = threadIdx.x;

    size_t sp = ((size_t)x * 128 + y) * 128 + z;
    size_t g  = (size_t)b * (size_t)VOX_ + sp;
    const float* E = eps + (size_t)b * 4 * (size_t)VOX_;

    float ex = E[sp];
    float ey = E[sp + (size_t)VOX_];
    float ez = E[sp + (size_t)VOX_ * 2];
    float ek = E[sp + (size_t)VOX_ * 3];
    float exm = (x > 0) ? E[sp - 16384]                 : EPS_OUT_C;
    float eym = (y > 0) ? E[sp + (size_t)VOX_ - 128]    : EPS_OUT_C;
    float ezm = (z > 0) ? E[sp + (size_t)VOX_ * 2 - 1]  : EPS_OUT_C;

    float lam = (ek - EPS_IN_C) / (EPS_OUT_C - EPS_IN_C);
    lam = fminf(fmaxf(lam, 0.0f), 1.0f);
    float denom = ex + exm + ey + eym + ez + ezm + KAPPA02_C * lam;

    float pxp = (x < 127) ? pin[g + 16384] : 0.0f;
    float pxm = (x > 0)   ? pin[g - 16384] : 0.0f;
    float pyp = (y < 127) ? pin[g + 128]   : 0.0f;
    float pym = (y > 0)   ? pin[g - 128]   : 0.0f;
    float pzp = (z < 127) ? pin[g + 1]     : 0.0f;
    float pzm = (z > 0)   ? pin[g - 1]     : 0.0f;

    float num = ex * pxp + exm * pxm + ey * pyp + eym * pym
              + ez * pzp + ezm * pzm + FOURPI_C * q[g];
    pout[g] = num / denom;
}

// ---------------- launch ----------------
extern "C" void kernel_launch(void* const* d_in, const int* in_sizes, int n_in,
                              void* d_out, int out_size, void* d_ws, size_t ws_size,
                              hipStream_t stream)
{
    const float* coords    = (const float*)d_in[0];
    const float* params    = (const float*)d_in[1];
    const int*   num_atoms = (const int*)d_in[2];

    float* q   = (float*)d_out;                       // [B][128^3]
    float* eps = q + (size_t)B_ * VOX_;               // [B][4][128^3]
    float* phi = eps + (size_t)B_ * 4 * VOX_;         // [B][128^3]

    hipMemsetAsync(q, 0, (size_t)B_ * VOX_ * sizeof(float), stream);
    hipMemsetAsync(phi, 0, (size_t)B_ * VOX_ * sizeof(float), stream);

    scatter_q_kernel<<<(B_ * N_ + 255) / 256, 256, 0, stream>>>(coords, params, num_atoms, q);
    eps_gather_v2<<<B_ * 4096, 512, 0, stream>>>(coords, params, num_atoms, eps);

    size_t coefBytes = (size_t)B_ * VOX_ * sizeof(uint4);              // 134 MB
    size_t need = coefBytes + (size_t)B_ * VOX_ * sizeof(float);       // +33.5 MB

    if (ws_size >= need) {
        uint4* coef = (uint4*)d_ws;
        float* tmp  = (float*)((char*)d_ws + coefBytes);
        coef_pack<<<B_ * 128 * 128, 128, 0, stream>>>(eps, q, coef);
        int jb = (int)(B_ * VOX_ / 4 / 256);
        const float* cur = phi;     // zeroed phi_0
        for (int it = 1; it <= 20; ++it) {
            float* dst = (it & 1) ? tmp : phi;   // iter 20 (even) -> phi (d_out)
            jacobi_v3<<<jb, 256, 0, stream>>>(coef, cur, dst);
            cur = dst;
        }
    } else {
        float* tmp = (float*)d_ws;
        int jb = B_ * 128 * 128;
        const float* cur = phi;
        for (int it = 1; it <= 20; ++it) {
            float* dst = (it & 1) ? tmp : phi;
            jacobi_v2<<<jb, 128, 0, stream>>>(eps, q, cur, dst);
            cur = dst;
        }
    }
}